// Round 7
// baseline (372.310 us; speedup 1.0000x reference)
//
#include <hip/hip_runtime.h>
#include <hip/hip_bf16.h>

// Problem constants
#define B_   2
#define S_   2048
#define H_   2048
#define NH_  16
#define G_   4
#define HD_  128
#define NPG_ 4
#define MROWS_ (B_ * S_)   // 4096
#define KVC_   (G_ * HD_)  // 512
#define NT_    (S_ / 64)   // 32 key/query tiles
#define QSCALE_ 0.08838834764831845f   // 1/sqrt(128)

typedef __attribute__((ext_vector_type(8))) short bf16x8;   // 8 bf16 = 4 VGPRs
typedef __attribute__((ext_vector_type(4))) float f32x4;

__device__ __forceinline__ short f2bf_s(float f) {
    __hip_bfloat16 h = __float2bfloat16(f);
    short s; __builtin_memcpy(&s, &h, 2); return s;
}

// global -> LDS direct copy, 16 B per lane (m97/m104 semantics):
// LDS dest = wave-uniform base + lane*16; global addr is per-lane.
__device__ __forceinline__ void gll16(const void* g, void* l) {
    __builtin_amdgcn_global_load_lds(
        (const __attribute__((address_space(1))) unsigned int*)g,
        (__attribute__((address_space(3))) unsigned int*)l, 16, 0, 0);
}

struct alignas(16) bf8pack { short s[8]; };
struct alignas(8)  s4pack  { short s[4]; };

__device__ __forceinline__ bf16x8 ld2x64(const short* p) {
    s4pack lo = *(const s4pack*)p;
    s4pack hi = *(const s4pack*)(p + 4);
    bf16x8 v;
    __builtin_memcpy(&v, &lo, 8);
    __builtin_memcpy((char*)&v + 8, &hi, 8);
    return v;
}

// ---------------------------------------------------------------------------
// Prep kernel. LDS writes now vectorized (4x ds_write_b64 per thread, was 16
// scalar b16); reads stay 4x4-microtile ds_read_b64; stores 8B coalesced.
// ---------------------------------------------------------------------------
__device__ __forceinline__ void tile_transpose64(
    const float* __restrict__ in, __hip_bfloat16* __restrict__ out,
    int R, int C, int bx, int by, int tid) {
    __shared__ short tile[64][68];
    const int r = tid >> 2, c0 = (tid & 3) * 16;
    const float4* src = (const float4*)(in + (size_t)(by * 64 + r) * C + bx * 64 + c0);
    float4 f0 = src[0], f1 = src[1], f2 = src[2], f3 = src[3];
    short pk0[16];
    pk0[0]  = f2bf_s(f0.x); pk0[1]  = f2bf_s(f0.y);
    pk0[2]  = f2bf_s(f0.z); pk0[3]  = f2bf_s(f0.w);
    pk0[4]  = f2bf_s(f1.x); pk0[5]  = f2bf_s(f1.y);
    pk0[6]  = f2bf_s(f1.z); pk0[7]  = f2bf_s(f1.w);
    pk0[8]  = f2bf_s(f2.x); pk0[9]  = f2bf_s(f2.y);
    pk0[10] = f2bf_s(f2.z); pk0[11] = f2bf_s(f2.w);
    pk0[12] = f2bf_s(f3.x); pk0[13] = f2bf_s(f3.y);
    pk0[14] = f2bf_s(f3.z); pk0[15] = f2bf_s(f3.w);
    short* tp = &tile[r][c0];               // 8B-aligned (c0%16==0, stride 136B)
    *(s4pack*)(tp)      = *(s4pack*)(pk0);
    *(s4pack*)(tp + 4)  = *(s4pack*)(pk0 + 4);
    *(s4pack*)(tp + 8)  = *(s4pack*)(pk0 + 8);
    *(s4pack*)(tp + 12) = *(s4pack*)(pk0 + 12);
    __syncthreads();
    // store: thread (a,q) handles source rows i0..i0+3 x cols j0..j0+3
    const int a = tid & 15, qq = tid >> 4;
    const int i0 = a * 4, j0 = qq * 4;
    s4pack r0v = *(const s4pack*)&tile[i0 + 0][j0];
    s4pack r1v = *(const s4pack*)&tile[i0 + 1][j0];
    s4pack r2v = *(const s4pack*)&tile[i0 + 2][j0];
    s4pack r3v = *(const s4pack*)&tile[i0 + 3][j0];
    #pragma unroll
    for (int c = 0; c < 4; ++c) {
        s4pack o;
        o.s[0] = r0v.s[c]; o.s[1] = r1v.s[c];
        o.s[2] = r2v.s[c]; o.s[3] = r3v.s[c];
        *(s4pack*)(out + (size_t)(bx * 64 + j0 + c) * R + by * 64 + i0) = o;
    }
}

__global__ __launch_bounds__(256) void prep(
    const float* __restrict__ x,  bf8pack* __restrict__ xb,
    const float* __restrict__ Wq, __hip_bfloat16* __restrict__ WqT,
    const float* __restrict__ Wk, __hip_bfloat16* __restrict__ WkT,
    const float* __restrict__ Wv, __hip_bfloat16* __restrict__ WvT,
    const float* __restrict__ Wo, __hip_bfloat16* __restrict__ WoT,
    const float* __restrict__ bq, const float* __restrict__ bk,
    const float* __restrict__ bv, float* __restrict__ bqkv) {
    const int bid = blockIdx.x, tid = threadIdx.x;
    if (bid < 4096) {                       // x convert (16B loads/stores)
        int i = bid * 256 + tid;
        const float4* p = (const float4*)(x + (size_t)i * 8);
        float4 a = p[0], c = p[1];
        bf8pack o;
        o.s[0] = f2bf_s(a.x); o.s[1] = f2bf_s(a.y);
        o.s[2] = f2bf_s(a.z); o.s[3] = f2bf_s(a.w);
        o.s[4] = f2bf_s(c.x); o.s[5] = f2bf_s(c.y);
        o.s[6] = f2bf_s(c.z); o.s[7] = f2bf_s(c.w);
        xb[i] = o;
    } else if (bid < 5120) {                // WqT: 32x32 tiles of 64
        int t = bid - 4096;
        tile_transpose64(Wq, WqT, H_, H_, t & 31, t >> 5, tid);
    } else if (bid < 5376) {                // WkT: 8x32 tiles
        int t = bid - 5120;
        tile_transpose64(Wk, WkT, H_, KVC_, t & 7, t >> 3, tid);
    } else if (bid < 5632) {                // WvT
        int t = bid - 5376;
        tile_transpose64(Wv, WvT, H_, KVC_, t & 7, t >> 3, tid);
    } else if (bid < 6656) {                // WoT
        int t = bid - 5632;
        tile_transpose64(Wo, WoT, H_, H_, t & 31, t >> 5, tid);
    } else {                                // bias concat
        int i = (bid - 6656) * 256 + tid;
        if (i < 3072)
            bqkv[i] = (i < 2048) ? bq[i] : (i < 2560) ? bk[i - 2048] : bv[i - 2560];
    }
}

// ===========================================================================
// 4-phase GEMM core — r4 structure, UNCHANGED (used by gemm_qkv8).
// ===========================================================================
template <int BM, int NF>
__device__ __forceinline__ void gemm_core(
    const __hip_bfloat16* __restrict__ A,
    const __hip_bfloat16* __restrict__ Bt,
    const int K, const int bm, const int bn,
    short* __restrict__ As, short* __restrict__ Bs,
    f32x4 (* __restrict__ acc)[NF])
{
    constexpr int MH  = BM / 64;
    constexpr int AI  = BM / 64;
    constexpr int NB2 = NF - 2;
    constexpr int STG = AI + NF;
    constexpr int ASZ = BM * 64;
    constexpr int BSZ = 64 * NF * 64;
    const int t0 = threadIdx.x;
    const int lane = t0 & 63, wave = t0 >> 6;
    const int l15 = lane & 15, quad = lane >> 4;
    const int lrow = lane >> 3, lcg = lane & 7;
    const int wm = (wave >> 2) * (BM / 2);
    const int wn = (wave & 3) * (16 * NF);
    const int nt = K >> 6;

    auto stage = [&](int ti) {
        const int kt = ti << 6;
        short* Ad = As + (ti & 1) * ASZ;
        short* Bd = Bs + (ti & 1) * BSZ;
        #pragma unroll
        for (int p = 0; p < AI; ++p) {
            const int r0 = wave * (AI * 8) + p * 8;
            const int row = r0 + lrow;
            gll16(A + (size_t)(bm + row) * K + kt + ((lcg ^ (row & 7)) << 3),
                  Ad + r0 * 64);
        }
        #pragma unroll
        for (int p = 0; p < NF; ++p) {
            const int r0 = wave * (NF * 8) + p * 8;
            const int row = r0 + lrow;
            gll16(Bt + (size_t)(bn + row) * K + kt + ((lcg ^ (row & 7)) << 3),
                  Bd + r0 * 64);
        }
    };

    auto waitcnt_stg = [&]() {
        if constexpr (STG == 7)      asm volatile("s_waitcnt vmcnt(7)" ::: "memory");
        else if constexpr (STG == 6) asm volatile("s_waitcnt vmcnt(6)" ::: "memory");
        else if constexpr (STG == 8) asm volatile("s_waitcnt vmcnt(8)" ::: "memory");
        else                         asm volatile("s_waitcnt vmcnt(0)" ::: "memory");
    };

    stage(0); stage(1);
    waitcnt_stg();
    asm volatile("s_barrier" ::: "memory");

    for (int t = 0; t < nt; ++t) {
        const short* Ab = As + (t & 1) * ASZ;
        const short* Bb = Bs + (t & 1) * BSZ;
        bf16x8 bg1[2][2], bg2[NB2][2], ah[MH][2];

        // ---- P1: read Bg1 + A-low ----
        #pragma unroll
        for (int n = 0; n < 2; ++n) {
            const int rb = wn + n * 16 + l15;
            #pragma unroll
            for (int ks = 0; ks < 2; ++ks)
                bg1[n][ks] = *(const bf16x8*)(Bb + rb * 64 +
                    (((ks * 4 + quad) ^ (rb & 7)) << 3));
        }
        #pragma unroll
        for (int i = 0; i < MH; ++i) {
            const int ra = wm + i * 16 + l15;
            #pragma unroll
            for (int ks = 0; ks < 2; ++ks)
                ah[i][ks] = *(const bf16x8*)(Ab + ra * 64 +
                    (((ks * 4 + quad) ^ (ra & 7)) << 3));
        }
        asm volatile("s_barrier" ::: "memory");
        asm volatile("s_waitcnt lgkmcnt(0)" ::: "memory");
        __builtin_amdgcn_s_setprio(1);
        #pragma unroll
        for (int ks = 0; ks < 2; ++ks)
            #pragma unroll
            for (int i = 0; i < MH; ++i)
                #pragma unroll
                for (int n = 0; n < 2; ++n)
                    acc[i][n] = __builtin_amdgcn_mfma_f32_16x16x32_bf16(
                        ah[i][ks], bg1[n][ks], acc[i][n], 0, 0, 0);
        __builtin_amdgcn_s_setprio(0);
        asm volatile("s_barrier" ::: "memory");

        // ---- P2: read B group 2 ----
        #pragma unroll
        for (int n = 0; n < NB2; ++n) {
            const int rb = wn + (2 + n) * 16 + l15;
            #pragma unroll
            for (int ks = 0; ks < 2; ++ks)
                bg2[n][ks] = *(const bf16x8*)(Bb + rb * 64 +
                    (((ks * 4 + quad) ^ (rb & 7)) << 3));
        }
        asm volatile("s_barrier" ::: "memory");
        asm volatile("s_waitcnt lgkmcnt(0)" ::: "memory");
        __builtin_amdgcn_s_setprio(1);
        #pragma unroll
        for (int ks = 0; ks < 2; ++ks)
            #pragma unroll
            for (int i = 0; i < MH; ++i)
                #pragma unroll
                for (int n = 0; n < NB2; ++n)
                    acc[i][2 + n] = __builtin_amdgcn_mfma_f32_16x16x32_bf16(
                        ah[i][ks], bg2[n][ks], acc[i][2 + n], 0, 0, 0);
        __builtin_amdgcn_s_setprio(0);
        asm volatile("s_barrier" ::: "memory");

        // ---- P3: read A-high (reuse ah regs) ----
        #pragma unroll
        for (int i = 0; i < MH; ++i) {
            const int ra = wm + (MH + i) * 16 + l15;
            #pragma unroll
            for (int ks = 0; ks < 2; ++ks)
                ah[i][ks] = *(const bf16x8*)(Ab + ra * 64 +
                    (((ks * 4 + quad) ^ (ra & 7)) << 3));
        }
        asm volatile("s_barrier" ::: "memory");
        asm volatile("s_waitcnt lgkmcnt(0)" ::: "memory");
        __builtin_amdgcn_s_setprio(1);
        #pragma unroll
        for (int ks = 0; ks < 2; ++ks)
            #pragma unroll
            for (int i = 0; i < MH; ++i)
                #pragma unroll
                for (int n = 0; n < NB2; ++n)
                    acc[MH + i][2 + n] = __builtin_amdgcn_mfma_f32_16x16x32_bf16(
                        ah[i][ks], bg2[n][ks], acc[MH + i][2 + n], 0, 0, 0);
        __builtin_amdgcn_s_setprio(0);
        asm volatile("s_barrier" ::: "memory");

        // ---- P4: stage t+2 into the freed buffer; MFMA regs-only ----
        if (t + 2 < nt) stage(t + 2);
        __builtin_amdgcn_s_setprio(1);
        #pragma unroll
        for (int ks = 0; ks < 2; ++ks)
            #pragma unroll
            for (int i = 0; i < MH; ++i)
                #pragma unroll
                for (int n = 0; n < 2; ++n)
                    acc[MH + i][n] = __builtin_amdgcn_mfma_f32_16x16x32_bf16(
                        ah[i][ks], bg1[n][ks], acc[MH + i][n], 0, 0, 0);
        __builtin_amdgcn_s_setprio(0);

        if (t + 2 < nt) {
            waitcnt_stg();
            asm volatile("s_barrier" ::: "memory");
        } else if (t + 1 < nt) {
            asm volatile("s_waitcnt vmcnt(0)" ::: "memory");
            asm volatile("s_barrier" ::: "memory");
        }
    }
}

// ===========================================================================
// NF=2 GEMM core: 256x128 tile, 2 regions/K-tile with 16-MFMA clusters
// (replaces the thin 8-MFMA phases of BM=128/NF=4 for gemm_out).
//   R1: read bg(4)+A-low(8); bar; lgkm0; prio; 16 MFMA; prio; bar
//   R2: read A-high(8); lgkm0; bar  [all buf-t reads certified]
//       stage(t+2); prio; 16 MFMA; prio; vmcnt(6); bar
// ===========================================================================
__device__ __forceinline__ void gemm_core_nf2(
    const __hip_bfloat16* __restrict__ A,
    const __hip_bfloat16* __restrict__ Bt,
    const int K, const int bm, const int bn,
    short* __restrict__ As, short* __restrict__ Bs,
    f32x4 (* __restrict__ acc)[2])
{
    constexpr int ASZ = 256 * 64;
    constexpr int BSZ = 128 * 64;
    const int t0 = threadIdx.x;
    const int lane = t0 & 63, wave = t0 >> 6;
    const int l15 = lane & 15, quad = lane >> 4;
    const int lrow = lane >> 3, lcg = lane & 7;
    const int wm = (wave >> 2) * 128;
    const int wn = (wave & 3) * 32;
    const int nt = K >> 6;

    auto stage = [&](int ti) {
        const int kt = ti << 6;
        short* Ad = As + (ti & 1) * ASZ;
        short* Bd = Bs + (ti & 1) * BSZ;
        #pragma unroll
        for (int p = 0; p < 4; ++p) {
            const int r0 = wave * 32 + p * 8;
            const int row = r0 + lrow;
            gll16(A + (size_t)(bm + row) * K + kt + ((lcg ^ (row & 7)) << 3),
                  Ad + r0 * 64);
        }
        #pragma unroll
        for (int p = 0; p < 2; ++p) {
            const int r0 = wave * 16 + p * 8;
            const int row = r0 + lrow;
            gll16(Bt + (size_t)(bn + row) * K + kt + ((lcg ^ (row & 7)) << 3),
                  Bd + r0 * 64);
        }
    };

    stage(0); stage(1);
    asm volatile("s_waitcnt vmcnt(6)" ::: "memory");
    asm volatile("s_barrier" ::: "memory");

    for (int t = 0; t < nt; ++t) {
        const short* Ab = As + (t & 1) * ASZ;
        const short* Bb = Bs + (t & 1) * BSZ;
        bf16x8 bg[2][2], ah[4][2];

        // ---- R1: read B (all) + A-low ----
        #pragma unroll
        for (int n = 0; n < 2; ++n) {
            const int rb = wn + n * 16 + l15;
            #pragma unroll
            for (int ks = 0; ks < 2; ++ks)
                bg[n][ks] = *(const bf16x8*)(Bb + rb * 64 +
                    (((ks * 4 + quad) ^ (rb & 7)) << 3));
        }
        #pragma unroll
        for (int i = 0; i < 4; ++i) {
            const int ra = wm + i * 16 + l15;
            #pragma unroll
            for (int ks = 0; ks < 2; ++ks)
                ah[i][ks] = *(const bf16x8*)(Ab + ra * 64 +
                    (((ks * 4 + quad) ^ (ra & 7)) << 3));
        }
        asm volatile("s_barrier" ::: "memory");
        asm volatile("s_waitcnt lgkmcnt(0)" ::: "memory");
        __builtin_amdgcn_s_setprio(1);
        #pragma unroll
        for (int ks = 0; ks < 2; ++ks)
            #pragma unroll
            for (int i = 0; i < 4; ++i)
                #pragma unroll
                for (int n = 0; n < 2; ++n)
                    acc[i][n] = __builtin_amdgcn_mfma_f32_16x16x32_bf16(
                        ah[i][ks], bg[n][ks], acc[i][n], 0, 0, 0);
        __builtin_amdgcn_s_setprio(0);
        asm volatile("s_barrier" ::: "memory");

        // ---- R2: read A-high; certify ALL buf-t reads; stage; MFMA ----
        #pragma unroll
        for (int i = 0; i < 4; ++i) {
            const int ra = wm + (4 + i) * 16 + l15;
            #pragma unroll
            for (int ks = 0; ks < 2; ++ks)
                ah[i][ks] = *(const bf16x8*)(Ab + ra * 64 +
                    (((ks * 4 + quad) ^ (ra & 7)) << 3));
        }
        asm volatile("s_waitcnt lgkmcnt(0)" ::: "memory");   // reads done...
        asm volatile("s_barrier" ::: "memory");              // ...for ALL waves
        if (t + 2 < nt) stage(t + 2);                        // buf t now dead
        __builtin_amdgcn_s_setprio(1);
        #pragma unroll
        for (int ks = 0; ks < 2; ++ks)
            #pragma unroll
            for (int i = 0; i < 4; ++i)
                #pragma unroll
                for (int n = 0; n < 2; ++n)
                    acc[4 + i][n] = __builtin_amdgcn_mfma_f32_16x16x32_bf16(
                        ah[i][ks], bg[n][ks], acc[4 + i][n], 0, 0, 0);
        __builtin_amdgcn_s_setprio(0);
        // certify stage(t+1) (issued one tile ago); leave stage(t+2) in flight
        if (t + 2 < nt) {
            asm volatile("s_waitcnt vmcnt(6)" ::: "memory");
            asm volatile("s_barrier" ::: "memory");
        } else if (t + 1 < nt) {
            asm volatile("s_waitcnt vmcnt(0)" ::: "memory");
            asm volatile("s_barrier" ::: "memory");
        }
    }
}

// ---------------------------------------------------------------------------
// Fused QKV GEMM, 256x192 tile -> grid 256 blocks (100% CU fill). Unchanged.
// ---------------------------------------------------------------------------
__global__ __launch_bounds__(512, 2) void gemm_qkv8(
    const __hip_bfloat16* __restrict__ A,
    const __hip_bfloat16* __restrict__ Bt,
    const float* __restrict__ bias,
    __hip_bfloat16* __restrict__ Qo,
    __hip_bfloat16* __restrict__ Ko,
    __hip_bfloat16* __restrict__ VtG) {
    __shared__ __align__(16) short As[2 * 256 * 64];   // 64 KB
    __shared__ __align__(16) short Bs[2 * 192 * 64];   // 48 KB
    const int bid = blockIdx.x;
    const int s = (bid & 7) * 32 + (bid >> 3);         // XCD-chunked remap
    const int bm = (s & 15) * 256, bn = (s >> 4) * 192;

    f32x4 acc[8][3] = {};
    gemm_core<256, 3>(A, Bt, H_, bm, bn, As, Bs, acc);

    const int t = threadIdx.x;
    const int lane = t & 63, wave = t >> 6;
    const int l15 = lane & 15, quad = lane >> 4;
    const int wm = (wave >> 2) * 128, wn = (wave & 3) * 48;

    #pragma unroll
    for (int i = 0; i < 8; ++i) {
        int row0 = bm + wm + i * 16 + quad * 4;
        #pragma unroll
        for (int j = 0; j < 3; ++j) {
            int c0 = bn + wn + j * 16;        // fragment col base (uniform)
            int colg = c0 + l15;
            float bv = bias[colg];
            if (c0 < 2048) {                  // Q: scaled, row-major
                #pragma unroll
                for (int r = 0; r < 4; ++r)
                    Qo[(size_t)(row0 + r) * H_ + colg] =
                        __float2bfloat16((acc[i][j][r] + bv) * QSCALE_);
            } else if (c0 < 2560) {           // K: row-major
                #pragma unroll
                for (int r = 0; r < 4; ++r)
                    Ko[(size_t)(row0 + r) * KVC_ + (colg - 2048)] =
                        __float2bfloat16(acc[i][j][r] + bv);
            } else {                          // V: transposed [kv_col][row]
                int coll = colg - 2560;
                short s4v[4];
                #pragma unroll
                for (int r = 0; r < 4; ++r) s4v[r] = f2bf_s(acc[i][j][r] + bv);
                *(uint2*)(&VtG[(size_t)coll * MROWS_ + row0]) = *(uint2*)s4v;
            }
        }
    }
}

// ---------------------------------------------------------------------------
// Output-projection GEMM, 256x128 tile (NF=2 thick-cluster core).
// grid 16x16=256 blocks (100% fill), fp32 out, XCD swizzle.
// ---------------------------------------------------------------------------
__global__ __launch_bounds__(512, 2) void gemm_out8(
    const __hip_bfloat16* __restrict__ A,
    const __hip_bfloat16* __restrict__ Bt,
    const float* __restrict__ bias,
    float* __restrict__ C) {
    __shared__ __align__(16) short As[2 * 256 * 64];   // 64 KB
    __shared__ __align__(16) short Bs[2 * 128 * 64];   // 32 KB
    const int bid = blockIdx.x;
    const int s = (bid & 7) * 32 + (bid >> 3);         // XCD-chunked remap
    const int bm = (s & 15) * 256, bn = (s >> 4) * 128;

    f32x4 acc[8][2] = {};
    gemm_core_nf2(A, Bt, H_, bm, bn, As, Bs, acc);

    const int t = threadIdx.x;
    const int lane = t & 63, wave = t >> 6;
    const int l15 = lane & 15, quad = lane >> 4;
    const int wm = (wave >> 2) * 128, wn = (wave & 3) * 32;

    #pragma unroll
    for (int i = 0; i < 8; ++i) {
        int row0 = bm + wm + i * 16 + quad * 4;
        #pragma unroll
        for (int j = 0; j < 2; ++j) {
            int col = bn + wn + j * 16 + l15;
            float bv = bias[col];
            #pragma unroll
            for (int r = 0; r < 4; ++r)
                C[(size_t)(row0 + r) * H_ + col] = acc[i][j][r] + bv;
        }
    }
}

// ---------------------------------------------------------------------------
// Flash attention (causal, GQA): SINGLE-buffered K and V (LDS 51 KB ->
// 3 blocks/CU, was 2), 4-barrier counted schedule. All waits target loads
// issued >=1 compute-phase earlier:
//   prologue: stageK(0), stageV(0)
//   per tile: vmcnt(4) [K ready] -> bar -> QK -> bar [K dead] -> stageK(t+1)
//             -> softmax -> vmcnt(4) [V ready] -> bar -> PV -> bar [V dead]
//             -> stageV(t+1)
// grid (B*NH=32, NT/2=16), block 256, launch_bounds(256,3).
// ---------------------------------------------------------------------------
__global__ __launch_bounds__(256, 3) void attn_causal_gqa(
    const __hip_bfloat16* __restrict__ Q,
    const __hip_bfloat16* __restrict__ K,
    const __hip_bfloat16* __restrict__ VtG,
    __hip_bfloat16* __restrict__ O) {
    __shared__ short KsL[64 * 128];      // [key][hd] swizzled, 16 KB
    __shared__ short VtL[128 * 64];      // [hd][key] swizzled, 16 KB
    __shared__ short Ps[4][2][16 * 76];  // [wave][qblk][qrow*76 + key], 19 KB

    const int h  = blockIdx.x;
    const int b  = h >> 4;
    const int hh = h & 15;
    const int g  = hh >> 2;
    const int qb1 = blockIdx.y;          // 0..15
    const int qb2 = NT_ - 1 - qb1;       // 31..16

    const int t = threadIdx.x;
    const int lane = t & 63, wave = t >> 6;
    const int l15 = lane & 15, quad = lane >> 4;
    const int swz = l15 & 7;

    const __hip_bfloat16* Qb = Q + (size_t)b * S_ * H_ + hh * HD_;
    const __hip_bfloat16* Kb = K + (size_t)b * S_ * KVC_ + g * HD_;
    const __hip_bfloat16* Vg = VtG + (size_t)g * HD_ * MROWS_ + b * S_;

    auto stageK = [&](int tile) {        // 4 gll16 per wave
        #pragma unroll
        for (int p = 0; p < 4; ++p) {
            int R0 = wave * 16 + p * 4;
            int row = R0 + (lane >> 4);
            int cg = ((lane & 15) ^ (row & 7)) * 8;
            gll16(Kb + (size_t)(tile * 64 + row) * KVC_ + cg, &KsL[R0 * 128]);
        }
    };
    auto stageV = [&](int tile) {        // 4 gll16 per wave
        #pragma unroll
        for (int p = 0; p < 4; ++p) {
            int R0 = wave * 32 + p * 8;
            int row = R0 + (lane >> 3);
            int cg = ((lane & 7) ^ (row & 7)) * 8;
            gll16(Vg + (size_t)row * MROWS_ + tile * 64 + cg, &VtL[R0 * 64]);
        }
    };

    // Q fragments (B-operand layout: n=l15=qrow, k=quad*8+j), persistent
    bf16x8 aq1[4], aq2[4];
    {
        const int qr1 = qb1 * 64 + wave * 16 + l15;
        const int qr2 = qb2 * 64 + wave * 16 + l15;
        #pragma unroll
        for (int kk = 0; kk < 4; ++kk) {
            aq1[kk] = *(const bf16x8*)(Qb + (size_t)qr1 * H_ + kk * 32 + quad * 8);
            aq2[kk] = *(const bf16x8*)(Qb + (size_t)qr2 * H_ + kk * 32 + quad * 8);
        }
    }

    f32x4 o1[8] = {}, o2[8] = {};
    float lp1 = 0.f, lp2 = 0.f;
    const int qrow_loc = wave * 16 + l15;   // this lane's q-row within q-block

    stageK(0); stageV(0);   // prologue: K0 (older) + V0 in flight

    for (int tile = 0; tile <= qb2; ++tile) {
        const bool do1 = (tile <= qb1);
        const bool last = (tile == qb2);

        // ---- K[tile] ready: retire own K loads (V stays in flight) ----
        asm volatile("s_waitcnt vmcnt(4)" ::: "memory");
        asm volatile("s_barrier" ::: "memory");

        // ---- S^T = K·Q^T: A=K frag (m=key), B=Q frag (n=qrow) ----
        f32x4 s2[4] = {}, s1[4] = {};
        #pragma unroll
        for (int kk = 0; kk < 4; ++kk) {
            bf16x8 bk[4];
            #pragma unroll
            for (int nt = 0; nt < 4; ++nt)
                bk[nt] = *(const bf16x8*)(
                    &KsL[(nt * 16 + l15) * 128 + (((kk * 4 + quad) ^ swz) * 8)]);
            #pragma unroll
            for (int nt = 0; nt < 4; ++nt)
                s2[nt] = __builtin_amdgcn_mfma_f32_16x16x32_bf16(
                    bk[nt], aq2[kk], s2[nt], 0, 0, 0);
            if (do1) {
                #pragma unroll
                for (int nt = 0; nt < 4; ++nt)
                    s1[nt] = __builtin_amdgcn_mfma_f32_16x16x32_bf16(
                        bk[nt], aq1[kk], s1[nt], 0, 0, 0);
            }
        }
        asm volatile("s_barrier" ::: "memory");   // all waves done reading K
        if (!last) stageK(tile + 1);              // K buffer free: restage

        // ---- softmax (no-max; Q pre-scaled) + packed Ps (wave-private) ----
        __asm__ volatile("" ::: "memory");
        short* P2 = &Ps[wave][1][0];
        {
            const bool m2 = (tile == qb2);
            #pragma unroll
            for (int nt = 0; nt < 4; ++nt) {
                s4pack pk;
                #pragma unroll
                for (int r = 0; r < 4; ++r) {
                    float p = __expf(s2[nt][r]);
                    if (m2 && (nt * 16 + quad * 4 + r > qrow_loc)) p = 0.f;
                    lp2 += p;
                    pk.s[r] = f2bf_s(p);
                }
                *(s4pack*)&P2[l15 * 76 + nt * 16 + quad * 4] = pk;
            }
        }
        short* P1 = &Ps[wave][0][0];
        if (do1) {
            const bool m1 = (tile == qb1);
            #pragma unroll
            for (int nt = 0; nt < 4; ++nt) {
                s4pack pk;
                #pragma unroll
                for (int r = 0; r < 4; ++r) {
                    float p = __expf(s1[nt][r]);
                    if (m1 && (nt * 16 + quad * 4 + r > qrow_loc)) p = 0.f;
                    lp1 += p;
                    pk.s[r] = f2bf_s(p);
                }
                *(s4pack*)&P1[l15 * 76 + nt * 16 + quad * 4] = pk;
            }
        }
        __asm__ volatile("" ::: "memory");

        // ---- V[tile] ready: retire own V loads (K[t+1] stays in flight) ----
        if (!last) asm volatile("s_waitcnt vmcnt(4)" ::: "memory");
        else       asm volatile("s_waitcnt vmcnt(0)" ::: "memory");
        asm volatile("s_barrier" ::: "memory");

        // ---- O += P·V: A=P (m=qrow), B=V^T frag (n=hd, k=key) ----
        #pragma unroll
        for (int ks = 0; ks < 2; ++ks) {
            bf16x8 ap2 = ld2x64(&P2[l15 * 76 + ks * 32 + quad * 8]);
            bf16x8 ap1;
            if (do1) ap1 = ld2x64(&P1[l15 * 76 + ks * 32 + quad * 8]);
            #pragma unroll
            for (int n2 = 0; n2 < 8; ++n2) {
                bf16x8 bv = *(const bf16x8*)(
                    &VtL[(n2 * 16 + l15) * 64 + (((ks * 4 + quad) ^ swz) * 8)]);
                o2[n2] = __builtin_amdgcn_mfma_f32_16x16x32_bf16(
                    ap2, bv, o2[n2], 0, 0, 0);
                if (do1)
                    o1[n2] = __builtin_amdgcn_mfma_f32_16x16x32_bf16(
                        ap1, bv, o1[n2], 0, 0, 0);
            }
        }
        asm volatile("s_barrier" ::: "memory");   // all waves done reading V
        if (!last) stageV(tile + 1);              // V buffer free: restage
    }

    // ---- epilogue: reduce l across quads (lanes l15, l15+16, +32, +48) ----
    float L1 = lp1, L2 = lp2;
    L1 += __shfl_xor(L1, 16); L2 += __shfl_xor(L2, 16);
    L1 += __shfl_xor(L1, 32); L2 += __shfl_xor(L2, 32);
    #pragma unroll
    for (int r = 0; r < 4; ++r) {
        // O acc C-layout: row = quad*4+r (q-row local), col = l15 (hd local)
        float i1 = 1.f / __shfl(L1, quad * 4 + r);
        float i2 = 1.f / __shfl(L2, quad * 4 + r);
        int s1r = qb1 * 64 + wave * 16 + quad * 4 + r;
        int s2r = qb2 * 64 + wave * 16 + quad * 4 + r;
        #pragma unroll
        for (int n2 = 0; n2 < 8; ++n2) {
            int d = n2 * 16 + l15;
            O[((size_t)b * S_ + s1r) * H_ + hh * HD_ + d] = __float2bfloat16(o1[n2][r] * i1);
            O[((size_t)b * S_ + s2r) * H_ + hh * HD_ + d] = __float2bfloat16(o2[n2][r] * i2);
        }
    }
}

// ---------------------------------------------------------------------------
// ws layout (44 MB + 12 KB):
//   [ 0,16)  xb  (dead after gemm_qkv) -> reused as Aws
//   [16,28)  WT  [3072][2048] bf16 (WqT/WkT/WvT)
//   [28,32)  Kws
//   [32,36)  VtG (V transposed [512][4096], written directly by gemm_qkv)
//   [36,44)  WoT
//   [44MB,+12KB) bqkv fp32[3072]
// Q (bf16) staged in d_out (fp32 buffer), overwritten by final GEMM.
// 4 dispatches total: prep -> gemm_qkv8 -> attn -> gemm_out8.
// ---------------------------------------------------------------------------
extern "C" void kernel_launch(void* const* d_in, const int* in_sizes, int n_in,
                              void* d_out, int out_size, void* d_ws, size_t ws_size,
                              hipStream_t stream) {
    const float* x  = (const float*)d_in[0];
    const float* Wq = (const float*)d_in[2];
    const float* bq = (const float*)d_in[3];
    const float* Wk = (const float*)d_in[4];
    const float* bk = (const float*)d_in[5];
    const float* Wv = (const float*)d_in[6];
    const float* bv = (const float*)d_in[7];
    const float* Wo = (const float*)d_in[8];
    const float* bo = (const float*)d_in[9];
    float* out = (float*)d_out;

    char* ws = (char*)d_ws;
    const size_t MB = 1024 * 1024;
    __hip_bfloat16* xb   = (__hip_bfloat16*)(ws);
    __hip_bfloat16* WT   = (__hip_bfloat16*)(ws + 16 * MB);
    __hip_bfloat16* Kws  = (__hip_bfloat16*)(ws + 28 * MB);
    __hip_bfloat16* VtG  = (__hip_bfloat16*)(ws + 32 * MB);
    __hip_bfloat16* WoT  = (__hip_bfloat16*)(ws + 36 * MB);
    float*          bqkv = (float*)         (ws + 44 * MB);
    __hip_bfloat16* Aws  = (__hip_bfloat16*)(ws);            // aliases xb
    __hip_bfloat16* Qbuf = (__hip_bfloat16*)d_out;

    // 0) fused prep: x-convert + 4 weight transposes (vectorized both ways)
    prep<<<6669, 256, 0, stream>>>(
        x, (bf8pack*)xb,
        Wq, WT,
        Wk, WT + (size_t)2048 * H_,
        Wv, WT + (size_t)2560 * H_,
        Wo, WoT,
        bq, bk, bv, bqkv);

    // 1) fused QKV projection (unchanged r4 core)
    gemm_qkv8<<<256, 512, 0, stream>>>(xb, WT, bqkv, Qbuf, Kws, VtG);

    // 2) causal GQA attention, 3 blocks/CU single-buffered counted pipeline
    attn_causal_gqa<<<dim3(B_ * NH_, NT_ / 2), 256, 0, stream>>>(Qbuf, Kws, VtG, Aws);

    // 3) output projection, 256x128 NF=2 thick-cluster core
    gemm_out8<<<256, 512, 0, stream>>>(Aws, WoT, bo, out);
}

// Round 8
// 291.656 us; speedup vs baseline: 1.2765x; 1.2765x over previous
//
#include <hip/hip_runtime.h>
#include <hip/hip_bf16.h>

// Problem constants
#define B_   2
#define S_   2048
#define H_   2048
#define NH_  16
#define G_   4
#define HD_  128
#define NPG_ 4
#define MROWS_ (B_ * S_)   // 4096
#define KVC_   (G_ * HD_)  // 512
#define NT_    (S_ / 64)   // 32 key/query tiles
#define QSCALE_ 0.08838834764831845f   // 1/sqrt(128)

typedef __attribute__((ext_vector_type(8))) short bf16x8;   // 8 bf16 = 4 VGPRs
typedef __attribute__((ext_vector_type(4))) float f32x4;

__device__ __forceinline__ short f2bf_s(float f) {
    __hip_bfloat16 h = __float2bfloat16(f);
    short s; __builtin_memcpy(&s, &h, 2); return s;
}

// global -> LDS direct copy, 16 B per lane (m97/m104 semantics):
// LDS dest = wave-uniform base + lane*16; global addr is per-lane.
__device__ __forceinline__ void gll16(const void* g, void* l) {
    __builtin_amdgcn_global_load_lds(
        (const __attribute__((address_space(1))) unsigned int*)g,
        (__attribute__((address_space(3))) unsigned int*)l, 16, 0, 0);
}

struct alignas(16) bf8pack { short s[8]; };
struct alignas(8)  s4pack  { short s[4]; };

__device__ __forceinline__ bf16x8 ld2x64(const short* p) {
    s4pack lo = *(const s4pack*)p;
    s4pack hi = *(const s4pack*)(p + 4);
    bf16x8 v;
    __builtin_memcpy(&v, &lo, 8);
    __builtin_memcpy((char*)&v + 8, &hi, 8);
    return v;
}

// ---------------------------------------------------------------------------
// Prep kernel (r6 version): vectorized LDS writes (b64), 4x4-microtile b64
// reads, 8B coalesced stores.
// ---------------------------------------------------------------------------
__device__ __forceinline__ void tile_transpose64(
    const float* __restrict__ in, __hip_bfloat16* __restrict__ out,
    int R, int C, int bx, int by, int tid) {
    __shared__ short tile[64][68];
    const int r = tid >> 2, c0 = (tid & 3) * 16;
    const float4* src = (const float4*)(in + (size_t)(by * 64 + r) * C + bx * 64 + c0);
    float4 f0 = src[0], f1 = src[1], f2 = src[2], f3 = src[3];
    short pk0[16];
    pk0[0]  = f2bf_s(f0.x); pk0[1]  = f2bf_s(f0.y);
    pk0[2]  = f2bf_s(f0.z); pk0[3]  = f2bf_s(f0.w);
    pk0[4]  = f2bf_s(f1.x); pk0[5]  = f2bf_s(f1.y);
    pk0[6]  = f2bf_s(f1.z); pk0[7]  = f2bf_s(f1.w);
    pk0[8]  = f2bf_s(f2.x); pk0[9]  = f2bf_s(f2.y);
    pk0[10] = f2bf_s(f2.z); pk0[11] = f2bf_s(f2.w);
    pk0[12] = f2bf_s(f3.x); pk0[13] = f2bf_s(f3.y);
    pk0[14] = f2bf_s(f3.z); pk0[15] = f2bf_s(f3.w);
    short* tp = &tile[r][c0];               // 8B-aligned (c0%16==0, stride 136B)
    *(s4pack*)(tp)      = *(s4pack*)(pk0);
    *(s4pack*)(tp + 4)  = *(s4pack*)(pk0 + 4);
    *(s4pack*)(tp + 8)  = *(s4pack*)(pk0 + 8);
    *(s4pack*)(tp + 12) = *(s4pack*)(pk0 + 12);
    __syncthreads();
    // store: thread (a,q) handles source rows i0..i0+3 x cols j0..j0+3
    const int a = tid & 15, qq = tid >> 4;
    const int i0 = a * 4, j0 = qq * 4;
    s4pack r0v = *(const s4pack*)&tile[i0 + 0][j0];
    s4pack r1v = *(const s4pack*)&tile[i0 + 1][j0];
    s4pack r2v = *(const s4pack*)&tile[i0 + 2][j0];
    s4pack r3v = *(const s4pack*)&tile[i0 + 3][j0];
    #pragma unroll
    for (int c = 0; c < 4; ++c) {
        s4pack o;
        o.s[0] = r0v.s[c]; o.s[1] = r1v.s[c];
        o.s[2] = r2v.s[c]; o.s[3] = r3v.s[c];
        *(s4pack*)(out + (size_t)(bx * 64 + j0 + c) * R + by * 64 + i0) = o;
    }
}

__global__ __launch_bounds__(256) void prep(
    const float* __restrict__ x,  bf8pack* __restrict__ xb,
    const float* __restrict__ Wq, __hip_bfloat16* __restrict__ WqT,
    const float* __restrict__ Wk, __hip_bfloat16* __restrict__ WkT,
    const float* __restrict__ Wv, __hip_bfloat16* __restrict__ WvT,
    const float* __restrict__ Wo, __hip_bfloat16* __restrict__ WoT,
    const float* __restrict__ bq, const float* __restrict__ bk,
    const float* __restrict__ bv, float* __restrict__ bqkv) {
    const int bid = blockIdx.x, tid = threadIdx.x;
    if (bid < 4096) {                       // x convert (16B loads/stores)
        int i = bid * 256 + tid;
        const float4* p = (const float4*)(x + (size_t)i * 8);
        float4 a = p[0], c = p[1];
        bf8pack o;
        o.s[0] = f2bf_s(a.x); o.s[1] = f2bf_s(a.y);
        o.s[2] = f2bf_s(a.z); o.s[3] = f2bf_s(a.w);
        o.s[4] = f2bf_s(c.x); o.s[5] = f2bf_s(c.y);
        o.s[6] = f2bf_s(c.z); o.s[7] = f2bf_s(c.w);
        xb[i] = o;
    } else if (bid < 5120) {                // WqT: 32x32 tiles of 64
        int t = bid - 4096;
        tile_transpose64(Wq, WqT, H_, H_, t & 31, t >> 5, tid);
    } else if (bid < 5376) {                // WkT: 8x32 tiles
        int t = bid - 5120;
        tile_transpose64(Wk, WkT, H_, KVC_, t & 7, t >> 3, tid);
    } else if (bid < 5632) {                // WvT
        int t = bid - 5376;
        tile_transpose64(Wv, WvT, H_, KVC_, t & 7, t >> 3, tid);
    } else if (bid < 6656) {                // WoT
        int t = bid - 5632;
        tile_transpose64(Wo, WoT, H_, H_, t & 31, t >> 5, tid);
    } else {                                // bias concat
        int i = (bid - 6656) * 256 + tid;
        if (i < 3072)
            bqkv[i] = (i < 2048) ? bq[i] : (i < 2560) ? bk[i - 2048] : bv[i - 2560];
    }
}

// ===========================================================================
// 4-phase GEMM core — r4 structure, UNCHANGED (used by gemm_qkv8).
// ===========================================================================
template <int BM, int NF>
__device__ __forceinline__ void gemm_core(
    const __hip_bfloat16* __restrict__ A,
    const __hip_bfloat16* __restrict__ Bt,
    const int K, const int bm, const int bn,
    short* __restrict__ As, short* __restrict__ Bs,
    f32x4 (* __restrict__ acc)[NF])
{
    constexpr int MH  = BM / 64;
    constexpr int AI  = BM / 64;
    constexpr int NB2 = NF - 2;
    constexpr int STG = AI + NF;
    constexpr int ASZ = BM * 64;
    constexpr int BSZ = 64 * NF * 64;
    const int t0 = threadIdx.x;
    const int lane = t0 & 63, wave = t0 >> 6;
    const int l15 = lane & 15, quad = lane >> 4;
    const int lrow = lane >> 3, lcg = lane & 7;
    const int wm = (wave >> 2) * (BM / 2);
    const int wn = (wave & 3) * (16 * NF);
    const int nt = K >> 6;

    auto stage = [&](int ti) {
        const int kt = ti << 6;
        short* Ad = As + (ti & 1) * ASZ;
        short* Bd = Bs + (ti & 1) * BSZ;
        #pragma unroll
        for (int p = 0; p < AI; ++p) {
            const int r0 = wave * (AI * 8) + p * 8;
            const int row = r0 + lrow;
            gll16(A + (size_t)(bm + row) * K + kt + ((lcg ^ (row & 7)) << 3),
                  Ad + r0 * 64);
        }
        #pragma unroll
        for (int p = 0; p < NF; ++p) {
            const int r0 = wave * (NF * 8) + p * 8;
            const int row = r0 + lrow;
            gll16(Bt + (size_t)(bn + row) * K + kt + ((lcg ^ (row & 7)) << 3),
                  Bd + r0 * 64);
        }
    };

    auto waitcnt_stg = [&]() {
        if constexpr (STG == 7)      asm volatile("s_waitcnt vmcnt(7)" ::: "memory");
        else if constexpr (STG == 6) asm volatile("s_waitcnt vmcnt(6)" ::: "memory");
        else if constexpr (STG == 8) asm volatile("s_waitcnt vmcnt(8)" ::: "memory");
        else                         asm volatile("s_waitcnt vmcnt(0)" ::: "memory");
    };

    stage(0); stage(1);
    waitcnt_stg();
    asm volatile("s_barrier" ::: "memory");

    for (int t = 0; t < nt; ++t) {
        const short* Ab = As + (t & 1) * ASZ;
        const short* Bb = Bs + (t & 1) * BSZ;
        bf16x8 bg1[2][2], bg2[NB2][2], ah[MH][2];

        // ---- P1: read Bg1 + A-low ----
        #pragma unroll
        for (int n = 0; n < 2; ++n) {
            const int rb = wn + n * 16 + l15;
            #pragma unroll
            for (int ks = 0; ks < 2; ++ks)
                bg1[n][ks] = *(const bf16x8*)(Bb + rb * 64 +
                    (((ks * 4 + quad) ^ (rb & 7)) << 3));
        }
        #pragma unroll
        for (int i = 0; i < MH; ++i) {
            const int ra = wm + i * 16 + l15;
            #pragma unroll
            for (int ks = 0; ks < 2; ++ks)
                ah[i][ks] = *(const bf16x8*)(Ab + ra * 64 +
                    (((ks * 4 + quad) ^ (ra & 7)) << 3));
        }
        asm volatile("s_barrier" ::: "memory");
        asm volatile("s_waitcnt lgkmcnt(0)" ::: "memory");
        __builtin_amdgcn_s_setprio(1);
        #pragma unroll
        for (int ks = 0; ks < 2; ++ks)
            #pragma unroll
            for (int i = 0; i < MH; ++i)
                #pragma unroll
                for (int n = 0; n < 2; ++n)
                    acc[i][n] = __builtin_amdgcn_mfma_f32_16x16x32_bf16(
                        ah[i][ks], bg1[n][ks], acc[i][n], 0, 0, 0);
        __builtin_amdgcn_s_setprio(0);
        asm volatile("s_barrier" ::: "memory");

        // ---- P2: read B group 2 ----
        #pragma unroll
        for (int n = 0; n < NB2; ++n) {
            const int rb = wn + (2 + n) * 16 + l15;
            #pragma unroll
            for (int ks = 0; ks < 2; ++ks)
                bg2[n][ks] = *(const bf16x8*)(Bb + rb * 64 +
                    (((ks * 4 + quad) ^ (rb & 7)) << 3));
        }
        asm volatile("s_barrier" ::: "memory");
        asm volatile("s_waitcnt lgkmcnt(0)" ::: "memory");
        __builtin_amdgcn_s_setprio(1);
        #pragma unroll
        for (int ks = 0; ks < 2; ++ks)
            #pragma unroll
            for (int i = 0; i < MH; ++i)
                #pragma unroll
                for (int n = 0; n < NB2; ++n)
                    acc[i][2 + n] = __builtin_amdgcn_mfma_f32_16x16x32_bf16(
                        ah[i][ks], bg2[n][ks], acc[i][2 + n], 0, 0, 0);
        __builtin_amdgcn_s_setprio(0);
        asm volatile("s_barrier" ::: "memory");

        // ---- P3: read A-high (reuse ah regs) ----
        #pragma unroll
        for (int i = 0; i < MH; ++i) {
            const int ra = wm + (MH + i) * 16 + l15;
            #pragma unroll
            for (int ks = 0; ks < 2; ++ks)
                ah[i][ks] = *(const bf16x8*)(Ab + ra * 64 +
                    (((ks * 4 + quad) ^ (ra & 7)) << 3));
        }
        asm volatile("s_barrier" ::: "memory");
        asm volatile("s_waitcnt lgkmcnt(0)" ::: "memory");
        __builtin_amdgcn_s_setprio(1);
        #pragma unroll
        for (int ks = 0; ks < 2; ++ks)
            #pragma unroll
            for (int i = 0; i < MH; ++i)
                #pragma unroll
                for (int n = 0; n < NB2; ++n)
                    acc[MH + i][2 + n] = __builtin_amdgcn_mfma_f32_16x16x32_bf16(
                        ah[i][ks], bg2[n][ks], acc[MH + i][2 + n], 0, 0, 0);
        __builtin_amdgcn_s_setprio(0);
        asm volatile("s_barrier" ::: "memory");

        // ---- P4: stage t+2 into the freed buffer; MFMA regs-only ----
        if (t + 2 < nt) stage(t + 2);
        __builtin_amdgcn_s_setprio(1);
        #pragma unroll
        for (int ks = 0; ks < 2; ++ks)
            #pragma unroll
            for (int i = 0; i < MH; ++i)
                #pragma unroll
                for (int n = 0; n < 2; ++n)
                    acc[MH + i][n] = __builtin_amdgcn_mfma_f32_16x16x32_bf16(
                        ah[i][ks], bg1[n][ks], acc[MH + i][n], 0, 0, 0);
        __builtin_amdgcn_s_setprio(0);

        if (t + 2 < nt) {
            waitcnt_stg();
            asm volatile("s_barrier" ::: "memory");
        } else if (t + 1 < nt) {
            asm volatile("s_waitcnt vmcnt(0)" ::: "memory");
            asm volatile("s_barrier" ::: "memory");
        }
    }
}

// ===========================================================================
// NF=2 GEMM core (gemm_out): 256x128 tile, 2 regions/K-tile, 16-MFMA clusters.
// ===========================================================================
__device__ __forceinline__ void gemm_core_nf2(
    const __hip_bfloat16* __restrict__ A,
    const __hip_bfloat16* __restrict__ Bt,
    const int K, const int bm, const int bn,
    short* __restrict__ As, short* __restrict__ Bs,
    f32x4 (* __restrict__ acc)[2])
{
    constexpr int ASZ = 256 * 64;
    constexpr int BSZ = 128 * 64;
    const int t0 = threadIdx.x;
    const int lane = t0 & 63, wave = t0 >> 6;
    const int l15 = lane & 15, quad = lane >> 4;
    const int lrow = lane >> 3, lcg = lane & 7;
    const int wm = (wave >> 2) * 128;
    const int wn = (wave & 3) * 32;
    const int nt = K >> 6;

    auto stage = [&](int ti) {
        const int kt = ti << 6;
        short* Ad = As + (ti & 1) * ASZ;
        short* Bd = Bs + (ti & 1) * BSZ;
        #pragma unroll
        for (int p = 0; p < 4; ++p) {
            const int r0 = wave * 32 + p * 8;
            const int row = r0 + lrow;
            gll16(A + (size_t)(bm + row) * K + kt + ((lcg ^ (row & 7)) << 3),
                  Ad + r0 * 64);
        }
        #pragma unroll
        for (int p = 0; p < 2; ++p) {
            const int r0 = wave * 16 + p * 8;
            const int row = r0 + lrow;
            gll16(Bt + (size_t)(bn + row) * K + kt + ((lcg ^ (row & 7)) << 3),
                  Bd + r0 * 64);
        }
    };

    stage(0); stage(1);
    asm volatile("s_waitcnt vmcnt(6)" ::: "memory");
    asm volatile("s_barrier" ::: "memory");

    for (int t = 0; t < nt; ++t) {
        const short* Ab = As + (t & 1) * ASZ;
        const short* Bb = Bs + (t & 1) * BSZ;
        bf16x8 bg[2][2], ah[4][2];

        // ---- R1: read B (all) + A-low ----
        #pragma unroll
        for (int n = 0; n < 2; ++n) {
            const int rb = wn + n * 16 + l15;
            #pragma unroll
            for (int ks = 0; ks < 2; ++ks)
                bg[n][ks] = *(const bf16x8*)(Bb + rb * 64 +
                    (((ks * 4 + quad) ^ (rb & 7)) << 3));
        }
        #pragma unroll
        for (int i = 0; i < 4; ++i) {
            const int ra = wm + i * 16 + l15;
            #pragma unroll
            for (int ks = 0; ks < 2; ++ks)
                ah[i][ks] = *(const bf16x8*)(Ab + ra * 64 +
                    (((ks * 4 + quad) ^ (ra & 7)) << 3));
        }
        asm volatile("s_barrier" ::: "memory");
        asm volatile("s_waitcnt lgkmcnt(0)" ::: "memory");
        __builtin_amdgcn_s_setprio(1);
        #pragma unroll
        for (int ks = 0; ks < 2; ++ks)
            #pragma unroll
            for (int i = 0; i < 4; ++i)
                #pragma unroll
                for (int n = 0; n < 2; ++n)
                    acc[i][n] = __builtin_amdgcn_mfma_f32_16x16x32_bf16(
                        ah[i][ks], bg[n][ks], acc[i][n], 0, 0, 0);
        __builtin_amdgcn_s_setprio(0);
        asm volatile("s_barrier" ::: "memory");

        // ---- R2: read A-high; certify ALL buf-t reads; stage; MFMA ----
        #pragma unroll
        for (int i = 0; i < 4; ++i) {
            const int ra = wm + (4 + i) * 16 + l15;
            #pragma unroll
            for (int ks = 0; ks < 2; ++ks)
                ah[i][ks] = *(const bf16x8*)(Ab + ra * 64 +
                    (((ks * 4 + quad) ^ (ra & 7)) << 3));
        }
        asm volatile("s_waitcnt lgkmcnt(0)" ::: "memory");   // reads done...
        asm volatile("s_barrier" ::: "memory");              // ...for ALL waves
        if (t + 2 < nt) stage(t + 2);                        // buf t now dead
        __builtin_amdgcn_s_setprio(1);
        #pragma unroll
        for (int ks = 0; ks < 2; ++ks)
            #pragma unroll
            for (int i = 0; i < 4; ++i)
                #pragma unroll
                for (int n = 0; n < 2; ++n)
                    acc[4 + i][n] = __builtin_amdgcn_mfma_f32_16x16x32_bf16(
                        ah[i][ks], bg[n][ks], acc[4 + i][n], 0, 0, 0);
        __builtin_amdgcn_s_setprio(0);
        if (t + 2 < nt) {
            asm volatile("s_waitcnt vmcnt(6)" ::: "memory");
            asm volatile("s_barrier" ::: "memory");
        } else if (t + 1 < nt) {
            asm volatile("s_waitcnt vmcnt(0)" ::: "memory");
            asm volatile("s_barrier" ::: "memory");
        }
    }
}

// ---------------------------------------------------------------------------
// Fused QKV GEMM, 256x192 tile -> grid 256 blocks (100% CU fill). Unchanged.
// ---------------------------------------------------------------------------
__global__ __launch_bounds__(512, 2) void gemm_qkv8(
    const __hip_bfloat16* __restrict__ A,
    const __hip_bfloat16* __restrict__ Bt,
    const float* __restrict__ bias,
    __hip_bfloat16* __restrict__ Qo,
    __hip_bfloat16* __restrict__ Ko,
    __hip_bfloat16* __restrict__ VtG) {
    __shared__ __align__(16) short As[2 * 256 * 64];   // 64 KB
    __shared__ __align__(16) short Bs[2 * 192 * 64];   // 48 KB
    const int bid = blockIdx.x;
    const int s = (bid & 7) * 32 + (bid >> 3);         // XCD-chunked remap
    const int bm = (s & 15) * 256, bn = (s >> 4) * 192;

    f32x4 acc[8][3] = {};
    gemm_core<256, 3>(A, Bt, H_, bm, bn, As, Bs, acc);

    const int t = threadIdx.x;
    const int lane = t & 63, wave = t >> 6;
    const int l15 = lane & 15, quad = lane >> 4;
    const int wm = (wave >> 2) * 128, wn = (wave & 3) * 48;

    #pragma unroll
    for (int i = 0; i < 8; ++i) {
        int row0 = bm + wm + i * 16 + quad * 4;
        #pragma unroll
        for (int j = 0; j < 3; ++j) {
            int c0 = bn + wn + j * 16;        // fragment col base (uniform)
            int colg = c0 + l15;
            float bv = bias[colg];
            if (c0 < 2048) {                  // Q: scaled, row-major
                #pragma unroll
                for (int r = 0; r < 4; ++r)
                    Qo[(size_t)(row0 + r) * H_ + colg] =
                        __float2bfloat16((acc[i][j][r] + bv) * QSCALE_);
            } else if (c0 < 2560) {           // K: row-major
                #pragma unroll
                for (int r = 0; r < 4; ++r)
                    Ko[(size_t)(row0 + r) * KVC_ + (colg - 2048)] =
                        __float2bfloat16(acc[i][j][r] + bv);
            } else {                          // V: transposed [kv_col][row]
                int coll = colg - 2560;
                short s4v[4];
                #pragma unroll
                for (int r = 0; r < 4; ++r) s4v[r] = f2bf_s(acc[i][j][r] + bv);
                *(uint2*)(&VtG[(size_t)coll * MROWS_ + row0]) = *(uint2*)s4v;
            }
        }
    }
}

// ---------------------------------------------------------------------------
// Output-projection GEMM, 256x128 tile (NF=2 core). grid 256, fp32 out.
// ---------------------------------------------------------------------------
__global__ __launch_bounds__(512, 2) void gemm_out8(
    const __hip_bfloat16* __restrict__ A,
    const __hip_bfloat16* __restrict__ Bt,
    const float* __restrict__ bias,
    float* __restrict__ C) {
    __shared__ __align__(16) short As[2 * 256 * 64];   // 64 KB
    __shared__ __align__(16) short Bs[2 * 128 * 64];   // 32 KB
    const int bid = blockIdx.x;
    const int s = (bid & 7) * 32 + (bid >> 3);         // XCD-chunked remap
    const int bm = (s & 15) * 256, bn = (s >> 4) * 128;

    f32x4 acc[8][2] = {};
    gemm_core_nf2(A, Bt, H_, bm, bn, As, Bs, acc);

    const int t = threadIdx.x;
    const int lane = t & 63, wave = t >> 6;
    const int l15 = lane & 15, quad = lane >> 4;
    const int wm = (wave >> 2) * 128, wn = (wave & 3) * 32;

    #pragma unroll
    for (int i = 0; i < 8; ++i) {
        int row0 = bm + wm + i * 16 + quad * 4;
        #pragma unroll
        for (int j = 0; j < 2; ++j) {
            int col = bn + wn + j * 16 + l15;
            float bv = bias[col];
            #pragma unroll
            for (int r = 0; r < 4; ++r)
                C[(size_t)(row0 + r) * H_ + col] = acc[i][j][r] + bv;
        }
    }
}

// ---------------------------------------------------------------------------
// Flash attention (causal, GQA), UNPAIRED q-blocks: grid (B*NH=32, NT=32) =
// 1024 blocks, each does ONE 64-row q-block. LDS 42.5 KB -> 3 blocks/CU;
// per-block state halved (o[8], one Ps set) -> VGPR ~75, no spill risk.
// Single-buffered K/V with counted per-wave vmcnt (r7 schedule, sans the
// launch_bounds(,3) spill): entry outstanding = {K[t],V[t]}, both >= one
// compute-phase old. Longest blocks (qb=31) launch first (LPT packing).
// ---------------------------------------------------------------------------
__global__ __launch_bounds__(256, 2) void attn_causal_gqa(
    const __hip_bfloat16* __restrict__ Q,
    const __hip_bfloat16* __restrict__ K,
    const __hip_bfloat16* __restrict__ VtG,
    __hip_bfloat16* __restrict__ O) {
    __shared__ short KsL[64 * 128];      // [key][hd] swizzled, 16 KB
    __shared__ short VtL[128 * 64];      // [hd][key] swizzled, 16 KB
    __shared__ short Ps[4][16 * 76];     // [wave][qrow*76 + key], 9.5 KB

    const int h  = blockIdx.x;
    const int b  = h >> 4;
    const int hh = h & 15;
    const int g  = hh >> 2;
    const int qb = NT_ - 1 - blockIdx.y; // 31..0, longest first

    const int t = threadIdx.x;
    const int lane = t & 63, wave = t >> 6;
    const int l15 = lane & 15, quad = lane >> 4;
    const int swz = l15 & 7;

    const __hip_bfloat16* Qb = Q + (size_t)b * S_ * H_ + hh * HD_;
    const __hip_bfloat16* Kb = K + (size_t)b * S_ * KVC_ + g * HD_;
    const __hip_bfloat16* Vg = VtG + (size_t)g * HD_ * MROWS_ + b * S_;

    auto stageK = [&](int tile) {        // 4 gll16 per wave
        #pragma unroll
        for (int p = 0; p < 4; ++p) {
            int R0 = wave * 16 + p * 4;
            int row = R0 + (lane >> 4);
            int cg = ((lane & 15) ^ (row & 7)) * 8;
            gll16(Kb + (size_t)(tile * 64 + row) * KVC_ + cg, &KsL[R0 * 128]);
        }
    };
    auto stageV = [&](int tile) {        // 4 gll16 per wave
        #pragma unroll
        for (int p = 0; p < 4; ++p) {
            int R0 = wave * 32 + p * 8;
            int row = R0 + (lane >> 3);
            int cg = ((lane & 7) ^ (row & 7)) * 8;
            gll16(Vg + (size_t)row * MROWS_ + tile * 64 + cg, &VtL[R0 * 64]);
        }
    };

    // Q fragments (B-operand layout: n=l15=qrow, k=quad*8+j), persistent
    bf16x8 aq[4];
    {
        const int qr = qb * 64 + wave * 16 + l15;
        #pragma unroll
        for (int kk = 0; kk < 4; ++kk)
            aq[kk] = *(const bf16x8*)(Qb + (size_t)qr * H_ + kk * 32 + quad * 8);
    }

    f32x4 o[8] = {};
    float lp = 0.f;
    const int qrow_loc = wave * 16 + l15;   // this lane's q-row within q-block

    stageK(0); stageV(0);   // prologue: K0 (older) + V0 in flight

    for (int tile = 0; tile <= qb; ++tile) {
        const bool last = (tile == qb);

        // ---- K[tile] ready (issued >=1 phase ago); V[tile] stays ----
        asm volatile("s_waitcnt vmcnt(4)" ::: "memory");
        asm volatile("s_barrier" ::: "memory");

        // ---- S^T = K·Q^T: A=K frag (m=key), B=Q frag (n=qrow) ----
        f32x4 s[4] = {};
        #pragma unroll
        for (int kk = 0; kk < 4; ++kk) {
            bf16x8 bk[4];
            #pragma unroll
            for (int nt = 0; nt < 4; ++nt)
                bk[nt] = *(const bf16x8*)(
                    &KsL[(nt * 16 + l15) * 128 + (((kk * 4 + quad) ^ swz) * 8)]);
            #pragma unroll
            for (int nt = 0; nt < 4; ++nt)
                s[nt] = __builtin_amdgcn_mfma_f32_16x16x32_bf16(
                    bk[nt], aq[kk], s[nt], 0, 0, 0);
        }
        asm volatile("s_barrier" ::: "memory");   // all waves done reading K
        if (!last) stageK(tile + 1);              // K buffer free: restage

        // ---- softmax (no-max; Q pre-scaled) + packed Ps (wave-private) ----
        __asm__ volatile("" ::: "memory");
        short* P = &Ps[wave][0];
        {
            #pragma unroll
            for (int nt = 0; nt < 4; ++nt) {
                s4pack pk;
                #pragma unroll
                for (int r = 0; r < 4; ++r) {
                    float p = __expf(s[nt][r]);
                    if (last && (nt * 16 + quad * 4 + r > qrow_loc)) p = 0.f;
                    lp += p;
                    pk.s[r] = f2bf_s(p);
                }
                *(s4pack*)&P[l15 * 76 + nt * 16 + quad * 4] = pk;
            }
        }
        __asm__ volatile("" ::: "memory");

        // ---- V[tile] ready (K[t+1] stays in flight) ----
        if (!last) asm volatile("s_waitcnt vmcnt(4)" ::: "memory");
        else       asm volatile("s_waitcnt vmcnt(0)" ::: "memory");
        asm volatile("s_barrier" ::: "memory");

        // ---- O += P·V: A=P (m=qrow), B=V^T frag (n=hd, k=key) ----
        #pragma unroll
        for (int ks = 0; ks < 2; ++ks) {
            bf16x8 ap = ld2x64(&P[l15 * 76 + ks * 32 + quad * 8]);
            #pragma unroll
            for (int n2 = 0; n2 < 8; ++n2) {
                bf16x8 bv = *(const bf16x8*)(
                    &VtL[(n2 * 16 + l15) * 64 + (((ks * 4 + quad) ^ swz) * 8)]);
                o[n2] = __builtin_amdgcn_mfma_f32_16x16x32_bf16(
                    ap, bv, o[n2], 0, 0, 0);
            }
        }
        asm volatile("s_barrier" ::: "memory");   // all waves done reading V
        if (!last) stageV(tile + 1);              // V buffer free: restage
    }

    // ---- epilogue: reduce l across quads (lanes l15, l15+16, +32, +48) ----
    float L = lp;
    L += __shfl_xor(L, 16);
    L += __shfl_xor(L, 32);
    #pragma unroll
    for (int r = 0; r < 4; ++r) {
        // O acc C-layout: row = quad*4+r (q-row local), col = l15 (hd local)
        float iv = 1.f / __shfl(L, quad * 4 + r);
        int srow = qb * 64 + wave * 16 + quad * 4 + r;
        #pragma unroll
        for (int n2 = 0; n2 < 8; ++n2) {
            int d = n2 * 16 + l15;
            O[((size_t)b * S_ + srow) * H_ + hh * HD_ + d] =
                __float2bfloat16(o[n2][r] * iv);
        }
    }
}

// ---------------------------------------------------------------------------
// ws layout (44 MB + 12 KB):
//   [ 0,16)  xb  (dead after gemm_qkv) -> reused as Aws
//   [16,28)  WT  [3072][2048] bf16 (WqT/WkT/WvT)
//   [28,32)  Kws
//   [32,36)  VtG (V transposed [512][4096], written directly by gemm_qkv)
//   [36,44)  WoT
//   [44MB,+12KB) bqkv fp32[3072]
// Q (bf16) staged in d_out (fp32 buffer), overwritten by final GEMM.
// 4 dispatches total: prep -> gemm_qkv8 -> attn -> gemm_out8.
// ---------------------------------------------------------------------------
extern "C" void kernel_launch(void* const* d_in, const int* in_sizes, int n_in,
                              void* d_out, int out_size, void* d_ws, size_t ws_size,
                              hipStream_t stream) {
    const float* x  = (const float*)d_in[0];
    const float* Wq = (const float*)d_in[2];
    const float* bq = (const float*)d_in[3];
    const float* Wk = (const float*)d_in[4];
    const float* bk = (const float*)d_in[5];
    const float* Wv = (const float*)d_in[6];
    const float* bv = (const float*)d_in[7];
    const float* Wo = (const float*)d_in[8];
    const float* bo = (const float*)d_in[9];
    float* out = (float*)d_out;

    char* ws = (char*)d_ws;
    const size_t MB = 1024 * 1024;
    __hip_bfloat16* xb   = (__hip_bfloat16*)(ws);
    __hip_bfloat16* WT   = (__hip_bfloat16*)(ws + 16 * MB);
    __hip_bfloat16* Kws  = (__hip_bfloat16*)(ws + 28 * MB);
    __hip_bfloat16* VtG  = (__hip_bfloat16*)(ws + 32 * MB);
    __hip_bfloat16* WoT  = (__hip_bfloat16*)(ws + 36 * MB);
    float*          bqkv = (float*)         (ws + 44 * MB);
    __hip_bfloat16* Aws  = (__hip_bfloat16*)(ws);            // aliases xb
    __hip_bfloat16* Qbuf = (__hip_bfloat16*)d_out;

    // 0) fused prep: x-convert + 4 weight transposes (vectorized both ways)
    prep<<<6669, 256, 0, stream>>>(
        x, (bf8pack*)xb,
        Wq, WT,
        Wk, WT + (size_t)2048 * H_,
        Wv, WT + (size_t)2560 * H_,
        Wo, WoT,
        bq, bk, bv, bqkv);

    // 1) fused QKV projection (unchanged r4 core)
    gemm_qkv8<<<256, 512, 0, stream>>>(xb, WT, bqkv, Qbuf, Kws, VtG);

    // 2) causal GQA attention, unpaired q-blocks, 3 blocks/CU
    attn_causal_gqa<<<dim3(B_ * NH_, NT_), 256, 0, stream>>>(Qbuf, Kws, VtG, Aws);

    // 3) output projection, 256x128 NF=2 core
    gemm_out8<<<256, 512, 0, stream>>>(Aws, WoT, bo, out);
}